// Round 2
// baseline (412.656 us; speedup 1.0000x reference)
//
#include <hip/hip_runtime.h>

// BitDelta chained layers: per layer W = base + bd*mask (4096x4096 fp32),
// x = x @ W with x [16,4096].  Pure weight-streaming, memory-bound.
//
// Per layer: grid (KCHUNKS=32, NCHUNKS=16) = 512 blocks, 512 threads (8 waves).
// Block tile: 128 k-rows x 256 cols.  Wave w owns 16 k-rows; lane owns 4 cols
// x 16 B-rows of accumulator.  Depth-4 prefetch ring keeps 8 float4 loads in
// flight per wave.  Waves tree-reduce in LDS (transposed layout, conflict-free),
// wave 0 atomicAdds the block partial (32 contributors per output element).

#define DD 4096
#define BB 16
#define KC 128                 // k-rows per block
#define CT 256                 // cols per block
#define TPB 512                // 8 waves
#define NWAVES 8
#define KW (KC / NWAVES)       // 16 k-rows per wave
#define VEC 4
#define KCHUNKS (DD / KC)      // 32
#define NCHUNKS (DD / CT)      // 16
#define PF 4                   // prefetch depth in k-rows

__global__ __launch_bounds__(TPB, 4)
void bitdelta_layer(const float* __restrict__ x,
                    const float* __restrict__ base,
                    const float* __restrict__ mask,
                    const float* __restrict__ bitdelta,
                    int layer,
                    float* __restrict__ out) {
    __shared__ float xs[BB][KC];        // 8 KB: x slice [16][128]
    __shared__ float red[64 * 256];     // 64 KB: [elem 0..63][slot 0..255]

    const int tid = threadIdx.x;
    const int w   = tid >> 6;           // wave id 0..7 = k-group
    const int l   = tid & 63;           // lane
    const int k0  = blockIdx.x * KC;
    const int c0  = blockIdx.y * CT + l * VEC;

    // Stage x[0:16][k0:k0+128]: 512 float4, one per thread, coalesced.
    {
        const int r  = tid >> 5;        // 0..15
        const int kk = (tid & 31) * 4;  // 0..124
        *reinterpret_cast<float4*>(&xs[r][kk]) =
            *reinterpret_cast<const float4*>(&x[r * DD + k0 + kk]);
    }
    __syncthreads();

    const float bd = bitdelta[layer];

    float acc[BB][VEC];
#pragma unroll
    for (int r = 0; r < BB; ++r)
#pragma unroll
        for (int j = 0; j < VEC; ++j) acc[r][j] = 0.0f;

    const float* bp = base + (size_t)(k0 + w * KW) * DD + c0;
    const float* mp = mask + (size_t)(k0 + w * KW) * DD + c0;

    // Prefetch ring, depth 4 (8 loads in flight).
    float4 pb[PF], pm[PF];
#pragma unroll
    for (int i = 0; i < PF; ++i) {
        pb[i] = *reinterpret_cast<const float4*>(bp + (size_t)i * DD);
        pm[i] = *reinterpret_cast<const float4*>(mp + (size_t)i * DD);
    }

#pragma unroll
    for (int i = 0; i < KW; ++i) {
        const float4 b = pb[i & (PF - 1)];   // compile-time index (full unroll)
        const float4 m = pm[i & (PF - 1)];
        if (i + PF < KW) {
            pb[i & (PF - 1)] = *reinterpret_cast<const float4*>(bp + (size_t)(i + PF) * DD);
            pm[i & (PF - 1)] = *reinterpret_cast<const float4*>(mp + (size_t)(i + PF) * DD);
        }
        const float w0 = fmaf(bd, m.x, b.x);
        const float w1 = fmaf(bd, m.y, b.y);
        const float w2 = fmaf(bd, m.z, b.z);
        const float w3 = fmaf(bd, m.w, b.w);
#pragma unroll
        for (int r = 0; r < BB; ++r) {
            const float xv = xs[r][w * KW + i];   // LDS broadcast (free)
            acc[r][0] = fmaf(xv, w0, acc[r][0]);
            acc[r][1] = fmaf(xv, w1, acc[r][1]);
            acc[r][2] = fmaf(xv, w2, acc[r][2]);
            acc[r][3] = fmaf(xv, w3, acc[r][3]);
        }
    }

    // Tree-reduce the 8 wave partials.  red layout is transposed
    // ([elem][slot]) so lane-consecutive slots hit consecutive banks.
#pragma unroll
    for (int step = NWAVES / 2; step >= 1; step >>= 1) {
        __syncthreads();
        if (w >= step && w < 2 * step) {
            const int slot = (w - step) * 64 + l;
#pragma unroll
            for (int r = 0; r < BB; ++r)
#pragma unroll
                for (int j = 0; j < VEC; ++j)
                    red[(r * VEC + j) * 256 + slot] = acc[r][j];
        }
        __syncthreads();
        if (w < step) {
            const int slot = w * 64 + l;
#pragma unroll
            for (int r = 0; r < BB; ++r)
#pragma unroll
                for (int j = 0; j < VEC; ++j)
                    acc[r][j] += red[(r * VEC + j) * 256 + slot];
        }
    }

    // Wave 0 holds the block partial: 64 atomics per lane, 32 contributing
    // blocks per output element.
    if (w == 0) {
#pragma unroll
        for (int r = 0; r < BB; ++r)
#pragma unroll
            for (int j = 0; j < VEC; ++j)
                atomicAdd(&out[r * DD + c0 + j], acc[r][j]);
    }
}

extern "C" void kernel_launch(void* const* d_in, const int* in_sizes, int n_in,
                              void* d_out, int out_size, void* d_ws, size_t ws_size,
                              hipStream_t stream) {
    const float* x    = (const float*)d_in[0];   // [16,4096]
    const float* base = (const float*)d_in[1];   // [4,4096,4096]
    const float* mask = (const float*)d_in[2];   // [4,4096,4096]
    const float* bd   = (const float*)d_in[3];   // [4]
    float* out = (float*)d_out;                  // [16,4096] fp32

    float* y0 = (float*)d_ws;                    // ping
    float* y1 = y0 + BB * DD;                    // pong

    const size_t act_bytes    = (size_t)BB * DD * sizeof(float);
    const size_t layer_stride = (size_t)DD * DD;

    const dim3 grid(KCHUNKS, NCHUNKS);

    hipMemsetAsync(y0, 0, act_bytes, stream);
    bitdelta_layer<<<grid, TPB, 0, stream>>>(x, base, mask, bd, 0, y0);

    hipMemsetAsync(y1, 0, act_bytes, stream);
    bitdelta_layer<<<grid, TPB, 0, stream>>>(y0, base + 1 * layer_stride,
                                             mask + 1 * layer_stride, bd, 1, y1);

    hipMemsetAsync(y0, 0, act_bytes, stream);
    bitdelta_layer<<<grid, TPB, 0, stream>>>(y1, base + 2 * layer_stride,
                                             mask + 2 * layer_stride, bd, 2, y0);

    hipMemsetAsync(out, 0, act_bytes, stream);
    bitdelta_layer<<<grid, TPB, 0, stream>>>(y0, base + 3 * layer_stride,
                                             mask + 3 * layer_stride, bd, 3, out);
}

// Round 3
// 179.352 us; speedup vs baseline: 2.3008x; 2.3008x over previous
//
#include <hip/hip_runtime.h>

// BitDelta chained layers: per layer W = base + bd*mask (4096x4096 fp32),
// x = x @ W, x [16,4096].  Weight-streaming, memory-bound (134 MB/layer).
//
// Structure: TPB=256 (4 waves), block tile = [KC=128 k-rows x CT=128 cols].
// Wave w owns 32 k-rows; lane owns 2 cols; acc[16][2] in VGPRs.
// x values are wave-uniform -> scalar (s_load) via readfirstlane-uniformized
// addressing; NO LDS and NO syncs in the k-loop.  2-row windows with
// distinct-register single-window prefetch.  4-wave LDS reduce (12 KB),
// wave 0 atomicAdds the block partial (32 contributors per element).

#define DD 4096
#define BB 16
#define KW 32                  // k-rows per wave
#define NW 4                   // waves per block
#define KC (KW * NW)           // 128 k-rows per block
#define VEC 2
#define CT 128                 // cols per block (64 lanes * VEC)
#define TPB 256
#define KCHUNKS (DD / KC)      // 32
#define NCHUNKS (DD / CT)      // 32

__global__ __launch_bounds__(TPB)
void bitdelta_layer(const float* __restrict__ x,
                    const float* __restrict__ base,
                    const float* __restrict__ mask,
                    const float* __restrict__ bitdelta,
                    int layer,
                    float* __restrict__ out) {
    __shared__ float red[16][3 * 64];   // 12 KB reduce buffer

    const int tid = threadIdx.x;
    const int l   = tid & 63;
    const int wid = __builtin_amdgcn_readfirstlane(tid >> 6);  // wave-uniform

    const int bid    = blockIdx.x;
    const int cchunk = bid & (NCHUNKS - 1);   // fastest: spread memory channels
    const int kchunk = bid >> 5;              // bid / NCHUNKS

    const int c0 = cchunk * CT + l * VEC;
    const int k0 = kchunk * KC + wid * KW;    // wave-uniform

    const float bd = bitdelta[layer];

    const float* wb = base + (size_t)k0 * DD + c0;
    const float* wm = mask + (size_t)k0 * DD + c0;
    const float* xp = x + k0;                 // wave-uniform base

    float acc[BB][VEC];
#pragma unroll
    for (int r = 0; r < BB; ++r)
#pragma unroll
        for (int c = 0; c < VEC; ++c) acc[r][c] = 0.0f;

    // Window 0 loads (float2 = 8 B/lane; wave instr = 512 B contiguous).
    float2 b0 = *reinterpret_cast<const float2*>(wb);
    float2 b1 = *reinterpret_cast<const float2*>(wb + DD);
    float2 m0 = *reinterpret_cast<const float2*>(wm);
    float2 m1 = *reinterpret_cast<const float2*>(wm + DD);

#pragma unroll
    for (int kw = 0; kw < KW; kw += 2) {
        float2 nb0, nb1, nm0, nm1;
        if (kw + 2 < KW) {   // compile-time after full unroll
            const float* pb = wb + (size_t)(kw + 2) * DD;
            const float* pm = wm + (size_t)(kw + 2) * DD;
            nb0 = *reinterpret_cast<const float2*>(pb);
            nb1 = *reinterpret_cast<const float2*>(pb + DD);
            nm0 = *reinterpret_cast<const float2*>(pm);
            nm1 = *reinterpret_cast<const float2*>(pm + DD);
        }

        const float w00 = fmaf(bd, m0.x, b0.x);   // W[kw][c0]
        const float w01 = fmaf(bd, m0.y, b0.y);   // W[kw][c0+1]
        const float w10 = fmaf(bd, m1.x, b1.x);   // W[kw+1][c0]
        const float w11 = fmaf(bd, m1.y, b1.y);   // W[kw+1][c0+1]

#pragma unroll
        for (int r = 0; r < BB; ++r) {
            // Wave-uniform addresses -> scalar loads (SMEM pipe), value is
            // the single SGPR operand of the v_fma.
            const float xv0 = xp[r * DD + kw];
            const float xv1 = xp[r * DD + kw + 1];
            acc[r][0] = fmaf(xv0, w00, acc[r][0]);
            acc[r][1] = fmaf(xv0, w01, acc[r][1]);
            acc[r][0] = fmaf(xv1, w10, acc[r][0]);
            acc[r][1] = fmaf(xv1, w11, acc[r][1]);
        }

        if (kw + 2 < KW) { b0 = nb0; b1 = nb1; m0 = nm0; m1 = nm1; }
    }

    // 4-wave reduce in two 16-element rounds (12 KB LDS, lane-consecutive
    // slots -> conflict-free).
#pragma unroll
    for (int t = 0; t < 2; ++t) {
        if (t) __syncthreads();
        if (wid != 0) {
#pragma unroll
            for (int e = 0; e < 16; ++e) {
                const int r = t * 8 + (e >> 1), c = e & 1;
                red[e][(wid - 1) * 64 + l] = acc[r][c];
            }
        }
        __syncthreads();
        if (wid == 0) {
#pragma unroll
            for (int e = 0; e < 16; ++e) {
                const int r = t * 8 + (e >> 1), c = e & 1;
                acc[r][c] += red[e][l] + red[e][64 + l] + red[e][128 + l];
            }
        }
    }

    if (wid == 0) {
#pragma unroll
        for (int r = 0; r < BB; ++r)
#pragma unroll
            for (int c = 0; c < VEC; ++c)
                atomicAdd(&out[r * DD + c0 + c], acc[r][c]);
    }
}

extern "C" void kernel_launch(void* const* d_in, const int* in_sizes, int n_in,
                              void* d_out, int out_size, void* d_ws, size_t ws_size,
                              hipStream_t stream) {
    const float* x    = (const float*)d_in[0];   // [16,4096]
    const float* base = (const float*)d_in[1];   // [4,4096,4096]
    const float* mask = (const float*)d_in[2];   // [4,4096,4096]
    const float* bd   = (const float*)d_in[3];   // [4]
    float* out = (float*)d_out;                  // [16,4096] fp32

    float* y0 = (float*)d_ws;
    float* y1 = y0 + BB * DD;

    const size_t act_bytes    = (size_t)BB * DD * sizeof(float);
    const size_t layer_stride = (size_t)DD * DD;
    const int    grid         = KCHUNKS * NCHUNKS;   // 1024

    hipMemsetAsync(y0, 0, act_bytes, stream);
    bitdelta_layer<<<grid, TPB, 0, stream>>>(x, base, mask, bd, 0, y0);

    hipMemsetAsync(y1, 0, act_bytes, stream);
    bitdelta_layer<<<grid, TPB, 0, stream>>>(y0, base + 1 * layer_stride,
                                             mask + 1 * layer_stride, bd, 1, y1);

    hipMemsetAsync(y0, 0, act_bytes, stream);
    bitdelta_layer<<<grid, TPB, 0, stream>>>(y1, base + 2 * layer_stride,
                                             mask + 2 * layer_stride, bd, 2, y0);

    hipMemsetAsync(out, 0, act_bytes, stream);
    bitdelta_layer<<<grid, TPB, 0, stream>>>(y0, base + 3 * layer_stride,
                                             mask + 3 * layer_stride, bd, 3, out);
}

// Round 4
// 170.534 us; speedup vs baseline: 2.4198x; 1.0517x over previous
//
#include <hip/hip_runtime.h>

// BitDelta chained layers: per layer W = base + bd*mask (4096x4096 fp32),
// x = x @ W, x [16,4096].  Weight-streaming, memory-bound (134 MB/layer).
//
// Stage 1 (per layer): grid 512 = (KCHUNKS=32 k-splits) x (NCHUNKS=16 col
// chunks), TPB=256 (4 waves).  Wave owns KW=32 k-rows; lane owns VEC=4 cols
// (float4 loads -> 1 KB/wave-instruction).  x read via wave-uniform scalar
// loads (no LDS, no syncs in k-loop).  4-wave LDS reduce; wave 0 writes the
// block partial to d_ws (NO atomics, NO memsets).
// Stage 2: 64-block kernel folds the 32 k-partials into the output.

#define DD 4096
#define BB 16
#define KW 32                  // k-rows per wave
#define NW 4                   // waves per block
#define KC (KW * NW)           // 128 k-rows per block
#define VEC 4
#define CT 256                 // cols per block (64 lanes * 4)
#define TPB 256
#define KCHUNKS (DD / KC)      // 32
#define NCHUNKS (DD / CT)      // 16
#define OUT_ELEMS (BB * DD)    // 65536

__global__ __launch_bounds__(TPB, 2)
void bitdelta_layer(const float* __restrict__ x,
                    const float* __restrict__ base,
                    const float* __restrict__ mask,
                    const float* __restrict__ bitdelta,
                    int layer,
                    float* __restrict__ part) {
    __shared__ float red[16][3 * 64];   // 12 KB reduce buffer

    const int tid = threadIdx.x;
    const int l   = tid & 63;
    const int wid = __builtin_amdgcn_readfirstlane(tid >> 6);  // wave-uniform

    const int bid    = blockIdx.x;
    const int cchunk = bid & (NCHUNKS - 1);
    const int kchunk = bid >> 4;              // bid / NCHUNKS

    const int c0 = cchunk * CT + l * VEC;
    const int k0 = kchunk * KC + wid * KW;    // wave-uniform

    const float bd = bitdelta[layer];

    const float* wb = base + (size_t)k0 * DD + c0;
    const float* wm = mask + (size_t)k0 * DD + c0;
    const float* xp = x + k0;                 // wave-uniform base

    float acc[BB][VEC];
#pragma unroll
    for (int r = 0; r < BB; ++r)
#pragma unroll
        for (int c = 0; c < VEC; ++c) acc[r][c] = 0.0f;

    // Window 0 (2 k-rows): float4 loads = 1 KB/wave-instruction.
    float4 b0 = *reinterpret_cast<const float4*>(wb);
    float4 b1 = *reinterpret_cast<const float4*>(wb + DD);
    float4 m0 = *reinterpret_cast<const float4*>(wm);
    float4 m1 = *reinterpret_cast<const float4*>(wm + DD);

#pragma unroll
    for (int kw = 0; kw < KW; kw += 2) {
        float4 nb0, nb1, nm0, nm1;
        if (kw + 2 < KW) {   // compile-time after full unroll
            const float* pb = wb + (size_t)(kw + 2) * DD;
            const float* pm = wm + (size_t)(kw + 2) * DD;
            nb0 = *reinterpret_cast<const float4*>(pb);
            nb1 = *reinterpret_cast<const float4*>(pb + DD);
            nm0 = *reinterpret_cast<const float4*>(pm);
            nm1 = *reinterpret_cast<const float4*>(pm + DD);
        }

        const float w00 = fmaf(bd, m0.x, b0.x);
        const float w01 = fmaf(bd, m0.y, b0.y);
        const float w02 = fmaf(bd, m0.z, b0.z);
        const float w03 = fmaf(bd, m0.w, b0.w);
        const float w10 = fmaf(bd, m1.x, b1.x);
        const float w11 = fmaf(bd, m1.y, b1.y);
        const float w12 = fmaf(bd, m1.z, b1.z);
        const float w13 = fmaf(bd, m1.w, b1.w);

#pragma unroll
        for (int r = 0; r < BB; ++r) {
            // Wave-uniform -> scalar loads on the SMEM pipe.
            const float xv0 = xp[r * DD + kw];
            const float xv1 = xp[r * DD + kw + 1];
            acc[r][0] = fmaf(xv0, w00, acc[r][0]);
            acc[r][1] = fmaf(xv0, w01, acc[r][1]);
            acc[r][2] = fmaf(xv0, w02, acc[r][2]);
            acc[r][3] = fmaf(xv0, w03, acc[r][3]);
            acc[r][0] = fmaf(xv1, w10, acc[r][0]);
            acc[r][1] = fmaf(xv1, w11, acc[r][1]);
            acc[r][2] = fmaf(xv1, w12, acc[r][2]);
            acc[r][3] = fmaf(xv1, w13, acc[r][3]);
        }

        if (kw + 2 < KW) { b0 = nb0; b1 = nb1; m0 = nm0; m1 = nm1; }
    }

    // 4-wave LDS reduce, four rounds of 16 elements (12 KB buffer,
    // lane-consecutive slots -> conflict-free).
#pragma unroll
    for (int t = 0; t < 4; ++t) {
        if (t) __syncthreads();
        if (wid != 0) {
#pragma unroll
            for (int e = 0; e < 16; ++e) {
                const int r = t * 4 + (e >> 2), c = e & 3;
                red[e][(wid - 1) * 64 + l] = acc[r][c];
            }
        }
        __syncthreads();
        if (wid == 0) {
#pragma unroll
            for (int e = 0; e < 16; ++e) {
                const int r = t * 4 + (e >> 2), c = e & 3;
                acc[r][c] += red[e][l] + red[e][64 + l] + red[e][128 + l];
            }
        }
    }

    // Wave 0 writes the block partial: [16][256] slab, float4 stores.
    if (wid == 0) {
        float* pp = part + (size_t)kchunk * OUT_ELEMS;
#pragma unroll
        for (int r = 0; r < BB; ++r) {
            const float4 v = make_float4(acc[r][0], acc[r][1], acc[r][2], acc[r][3]);
            *reinterpret_cast<float4*>(&pp[r * DD + c0]) = v;
        }
    }
}

// Stage 2: out[e] = sum_k part[k][e].  64 blocks x 256 threads x float4.
__global__ __launch_bounds__(256)
void reduce_partials(const float* __restrict__ part, float* __restrict__ out) {
    const int idx = (blockIdx.x * 256 + threadIdx.x) * 4;
    float4 a = *reinterpret_cast<const float4*>(&part[idx]);
#pragma unroll
    for (int k = 1; k < KCHUNKS; ++k) {
        const float4 p = *reinterpret_cast<const float4*>(
            &part[(size_t)k * OUT_ELEMS + idx]);
        a.x += p.x; a.y += p.y; a.z += p.z; a.w += p.w;
    }
    *reinterpret_cast<float4*>(&out[idx]) = a;
}

extern "C" void kernel_launch(void* const* d_in, const int* in_sizes, int n_in,
                              void* d_out, int out_size, void* d_ws, size_t ws_size,
                              hipStream_t stream) {
    const float* x    = (const float*)d_in[0];   // [16,4096]
    const float* base = (const float*)d_in[1];   // [4,4096,4096]
    const float* mask = (const float*)d_in[2];   // [4,4096,4096]
    const float* bd   = (const float*)d_in[3];   // [4]
    float* out = (float*)d_out;                  // [16,4096] fp32

    float* part = (float*)d_ws;                  // 32 x 65536 floats = 8 MB
    float* y0   = part + (size_t)KCHUNKS * OUT_ELEMS;
    float* y1   = y0 + OUT_ELEMS;

    const size_t layer_stride = (size_t)DD * DD;
    const int    grid1 = KCHUNKS * NCHUNKS;      // 512
    const int    grid2 = OUT_ELEMS / (256 * 4);  // 64

    bitdelta_layer<<<grid1, TPB, 0, stream>>>(x, base, mask, bd, 0, part);
    reduce_partials<<<grid2, 256, 0, stream>>>(part, y0);

    bitdelta_layer<<<grid1, TPB, 0, stream>>>(y0, base + 1 * layer_stride,
                                              mask + 1 * layer_stride, bd, 1, part);
    reduce_partials<<<grid2, 256, 0, stream>>>(part, y1);

    bitdelta_layer<<<grid1, TPB, 0, stream>>>(y1, base + 2 * layer_stride,
                                              mask + 2 * layer_stride, bd, 2, part);
    reduce_partials<<<grid2, 256, 0, stream>>>(part, y0);

    bitdelta_layer<<<grid1, TPB, 0, stream>>>(y0, base + 3 * layer_stride,
                                              mask + 3 * layer_stride, bd, 3, part);
    reduce_partials<<<grid2, 256, 0, stream>>>(part, out);
}